// Round 11
// baseline (198.132 us; speedup 1.0000x reference)
//
#include <hip/hip_runtime.h>
#include <hip/hip_fp16.h>

typedef _Float16 half8 __attribute__((ext_vector_type(8)));
typedef _Float16 half4 __attribute__((ext_vector_type(4)));
typedef float f32x4 __attribute__((ext_vector_type(4)));
typedef unsigned uint4v __attribute__((ext_vector_type(4)));

// ---------- binned CSR build ----------
#define RANGE    512
#define RSH      9
#define CAP      17408          // mean E/NB=16327 + 8 sigma
#define T_TILE   4096           // edges per binpass block (256 thr x 16)

__global__ void init_gcursor(int* __restrict__ gcursor, int NB) {
    int t = blockIdx.x * blockDim.x + threadIdx.x;
    if (t < NB) gcursor[t] = t * CAP;
}

__global__ __launch_bounds__(256) void binpass(const int* __restrict__ src,
                                               const int* __restrict__ dst, int E,
                                               int* __restrict__ gcursor,
                                               unsigned* __restrict__ pairbuf) {
    __shared__ unsigned sbuf[T_TILE];
    __shared__ unsigned char sbk[T_TILE];
    __shared__ int lcount[256], loff[256], lplace[256], gbase[256];
    int t = threadIdx.x;
    int base = blockIdx.x * T_TILE;
    int ecount = min(T_TILE, E - base);

    lcount[t] = 0;
    __syncthreads();

    unsigned pk[16];
    int bn[16];
#pragma unroll
    for (int k = 0; k < 16; ++k) {
        int i = base + t + k * 256;
        if (i < E) {
            int s = __builtin_nontemporal_load(src + i);
            int d = __builtin_nontemporal_load(dst + i);
            bn[k] = d >> RSH;
            pk[k] = ((unsigned)s << RSH) | (unsigned)(d & (RANGE - 1));
            atomicAdd(&lcount[bn[k]], 1);
        } else bn[k] = -1;
    }
    __syncthreads();
    loff[t] = lcount[t];
    __syncthreads();
    for (int off = 1; off < 256; off <<= 1) {
        int u = (t >= off) ? loff[t - off] : 0;
        __syncthreads();
        loff[t] += u;
        __syncthreads();
    }
    int ex = loff[t] - lcount[t];
    __syncthreads();
    loff[t] = ex;
    lplace[t] = ex;
    if (lcount[t] > 0) gbase[t] = atomicAdd(&gcursor[t], lcount[t]);
    __syncthreads();
#pragma unroll
    for (int k = 0; k < 16; ++k) {
        if (bn[k] >= 0) {
            int pos = atomicAdd(&lplace[bn[k]], 1);
            sbuf[pos] = pk[k];
            sbk[pos] = (unsigned char)bn[k];
        }
    }
    __syncthreads();
    for (int i = t; i < ecount; i += 256) {
        int b = sbk[i];
        pairbuf[gbase[b] + (i - loff[b])] = sbuf[i];
    }
}

__global__ __launch_bounds__(256) void bucketscan(const int* __restrict__ gcursor, int NB,
                                                  int* __restrict__ bbase,
                                                  int* __restrict__ rowptr, int N) {
    __shared__ int sd[256];
    int t = threadIdx.x;
    int c = (t < NB) ? (gcursor[t] - t * CAP) : 0;
    sd[t] = c;
    __syncthreads();
    for (int off = 1; off < 256; off <<= 1) {
        int u = (t >= off) ? sd[t - off] : 0;
        __syncthreads();
        sd[t] += u;
        __syncthreads();
    }
    if (t < NB) bbase[t] = sd[t] - c;
    if (t == 255) { bbase[NB] = sd[255]; rowptr[N] = sd[255]; }
}

__global__ __launch_bounds__(512) void bucket_build(const unsigned* __restrict__ pairbuf,
                                                    const int* __restrict__ gcursor,
                                                    const int* __restrict__ bbase, int N,
                                                    int* __restrict__ rowptr,
                                                    float* __restrict__ dinv,
                                                    int* __restrict__ eidx) {
    __shared__ int lcnt[RANGE];
    __shared__ int lsc[RANGE];
    int b = blockIdx.x, t = threadIdx.x;
    int cnt = gcursor[b] - b * CAP;
    const unsigned* pb = pairbuf + (size_t)b * CAP;

    lcnt[t] = 0;
    __syncthreads();
    for (int i = t; i < cnt; i += 512) atomicAdd(&lcnt[pb[i] & (RANGE - 1)], 1);
    __syncthreads();
    lsc[t] = lcnt[t];
    __syncthreads();
    for (int off = 1; off < 512; off <<= 1) {
        int u = (t >= off) ? lsc[t - off] : 0;
        __syncthreads();
        lsc[t] += u;
        __syncthreads();
    }
    int ex = lsc[t] - lcnt[t];
    int gb = bbase[b];
    int node = b * RANGE + t;
    if (node < N) {
        rowptr[node] = gb + ex;
        dinv[node] = rsqrtf((float)lcnt[t] + 1.0f);
    }
    __syncthreads();
    lsc[t] = gb + ex;
    __syncthreads();
    for (int i = t; i < cnt; i += 512) {
        unsigned p = pb[i];
        int pos = atomicAdd(&lsc[p & (RANGE - 1)], 1);
        eidx[pos] = (int)(p >> RSH);
    }
}

// ---------- helpers ----------

__device__ __forceinline__ void unp8(uint4v v, float* f) {
#pragma unroll
    for (int k = 0; k < 4; ++k) {
        unsigned w = v[k];
        __half2 h2 = *reinterpret_cast<__half2*>(&w);
        float2 t = __half22float2(h2);
        f[2 * k] = t.x; f[2 * k + 1] = t.y;
    }
}

__device__ __forceinline__ void acc8(float* a, uint4v v) {
#pragma unroll
    for (int k = 0; k < 4; ++k) {
        unsigned w = v[k];
        __half2 h2 = *reinterpret_cast<__half2*>(&w);
        float2 t = __half22float2(h2);
        a[2 * k]     += t.x;
        a[2 * k + 1] += t.y;
    }
}

__device__ __forceinline__ uint4v pk8(const float* o) {
    uint4v r;
#pragma unroll
    for (int k = 0; k < 4; ++k) {
        __half2 h2 = __floats2half2_rn(o[2 * k], o[2 * k + 1]);
        r[k] = *reinterpret_cast<unsigned*>(&h2);
    }
    return r;
}

// ---------------- GEMM1 via MFMA: g1 = fp16((x @ W1) * dinv[row]) ----------------

__global__ __launch_bounds__(256) void gemm1_mfma(const float* __restrict__ x,
                                                  const float* __restrict__ W1,
                                                  const float* __restrict__ dinv,
                                                  __half* __restrict__ g1, int N) {
    int wave = threadIdx.x >> 6;
    int lane = threadIdx.x & 63;
    int R0 = blockIdx.x * 64 + wave * 16;
    if (R0 >= N) return;
    int m = lane & 15;
    int kb = (lane >> 4) * 8;
    int row = R0 + m;
    int rowc = min(row, N - 1);

    half8 bfrag[4];
#pragma unroll
    for (int kk = 0; kk < 4; ++kk) {
#pragma unroll
        for (int j = 0; j < 8; ++j)
            bfrag[kk][j] = (_Float16)W1[(kk * 32 + kb + j) * 16 + m];
    }

    const float* xr = x + (size_t)rowc * 128;
    f32x4 u[8];
#pragma unroll
    for (int kk = 0; kk < 4; ++kk) {
        u[2 * kk]     = __builtin_nontemporal_load(reinterpret_cast<const f32x4*>(xr + kk * 32 + kb));
        u[2 * kk + 1] = __builtin_nontemporal_load(reinterpret_cast<const f32x4*>(xr + kk * 32 + kb + 4));
    }

    f32x4 acc = {0.f, 0.f, 0.f, 0.f};
#pragma unroll
    for (int kk = 0; kk < 4; ++kk) {
        half8 a;
#pragma unroll
        for (int j = 0; j < 4; ++j) {
            a[j]     = (_Float16)u[2 * kk][j];
            a[j + 4] = (_Float16)u[2 * kk + 1][j];
        }
        acc = __builtin_amdgcn_mfma_f32_16x16x32_f16(a, bfrag[kk], acc, 0, 0, 0);
    }

#pragma unroll
    for (int i = 0; i < 4; ++i) {
        int r = R0 + (lane >> 4) * 4 + i;
        if (r < N) g1[(size_t)r * 16 + m] = __float2half(acc[i] * dinv[r]);
    }
}

// ---------------- gather1: lane = (node, h, es); uint4 row-half loads, es edge-split ----------------

__global__ __launch_bounds__(256) void gather1_kernel(const int* __restrict__ rowptr,
                                                      const int* __restrict__ eidx,
                                                      const __half* __restrict__ g1,
                                                      const float* __restrict__ dinv,
                                                      const float* __restrict__ b1,
                                                      __half* __restrict__ g2, int N) {
    int gid = blockIdx.x * blockDim.x + threadIdx.x;
    int d = gid >> 2;
    if (d >= N) return;
    int sub = threadIdx.x & 3;
    int h = sub & 1, es = sub >> 1;
    int f0 = h * 8;
    int lo = rowptr[d], hi = rowptr[d + 1];
    float a[8] = {0, 0, 0, 0, 0, 0, 0, 0};
    int j = lo + es;
    for (; j + 2 < hi; j += 4) {
        int s0 = __builtin_nontemporal_load(eidx + j);
        int s1 = __builtin_nontemporal_load(eidx + j + 2);
        uint4v v0 = *reinterpret_cast<const uint4v*>(g1 + s0 * 16 + f0);
        uint4v v1 = *reinterpret_cast<const uint4v*>(g1 + s1 * 16 + f0);
        acc8(a, v0);
        acc8(a, v1);
    }
    for (; j < hi; j += 2) {
        int s = eidx[j];
        uint4v v = *reinterpret_cast<const uint4v*>(g1 + s * 16 + f0);
        acc8(a, v);
    }
#pragma unroll
    for (int k = 0; k < 8; ++k) a[k] += __shfl_xor(a[k], 2);
    if (es == 0) {
        float di = dinv[d];
        uint4v sv = *reinterpret_cast<const uint4v*>(g1 + d * 16 + f0);
        float sf[8];
        unp8(sv, sf);
        f32x4 bb0 = *reinterpret_cast<const f32x4*>(b1 + f0);
        f32x4 bb1 = *reinterpret_cast<const f32x4*>(b1 + f0 + 4);
        float o[8];
#pragma unroll
        for (int k = 0; k < 4; ++k) {
            o[k]     = fmaxf(di * (a[k] + sf[k]) + bb0[k], 0.0f) * di;
            o[k + 4] = fmaxf(di * (a[k + 4] + sf[k + 4]) + bb1[k], 0.0f) * di;
        }
        *reinterpret_cast<uint4v*>(g2 + d * 16 + f0) = pk8(o);
    }
}

// ---------------- fused gather2 + GEMM2 ----------------
// wave = 16 nodes. lane bits: nl=lane&15 (node), es=(lane>>4)&1 (edge slot), h=lane>>5 (feat half).
// After es-reduce (shfl_xor 16) every lane holds its half's full sums. A-fragment for
// mfma_f32_16x16x16_f16 (lane q=lane>>4 needs feats q*4..q*4+3 of half q>>1) is a 4-way select.
// D layout: col=lane&15, row=(lane>>4)*4+reg. out stores nontemporal (never re-read).

__global__ __launch_bounds__(256) void gather2_gemm2(const int* __restrict__ rowptr,
                                                     const int* __restrict__ eidx,
                                                     const __half* __restrict__ g2,
                                                     const float* __restrict__ dinv,
                                                     const float* __restrict__ W2,
                                                     const float* __restrict__ b2,
                                                     float* __restrict__ out, int N) {
    int gid = blockIdx.x * blockDim.x + threadIdx.x;
    int wid = gid >> 6;
    int lane = threadIdx.x & 63;
    int base = wid * 16;
    if (base >= N) return;
    int nl = lane & 15;
    int q = lane >> 4;
    int es = q & 1;
    int h = lane >> 5;
    int f0 = h * 8;
    int d = base + nl;
    int dc = min(d, N - 1);
    int lo = rowptr[dc], hi = rowptr[dc + 1];

    float a[8] = {0, 0, 0, 0, 0, 0, 0, 0};
    int j = lo + es;
    for (; j + 2 < hi; j += 4) {
        int s0 = __builtin_nontemporal_load(eidx + j);
        int s1 = __builtin_nontemporal_load(eidx + j + 2);
        uint4v v0 = *reinterpret_cast<const uint4v*>(g2 + s0 * 16 + f0);
        uint4v v1 = *reinterpret_cast<const uint4v*>(g2 + s1 * 16 + f0);
        acc8(a, v0);
        acc8(a, v1);
    }
    for (; j < hi; j += 2) {
        int s = eidx[j];
        uint4v v = *reinterpret_cast<const uint4v*>(g2 + s * 16 + f0);
        acc8(a, v);
    }
#pragma unroll
    for (int k = 0; k < 8; ++k) a[k] += __shfl_xor(a[k], 16);

    float di = dinv[dc];
    uint4v sv = *reinterpret_cast<const uint4v*>(g2 + dc * 16 + f0);
    float sf[8];
    unp8(sv, sf);
    float af[8];
#pragma unroll
    for (int k = 0; k < 8; ++k) af[k] = di * (a[k] + sf[k]);

    int hi4 = (q & 1) * 4;
    half4 afrag;
#pragma unroll
    for (int jj = 0; jj < 4; ++jj) afrag[jj] = (_Float16)af[hi4 + jj];

    f32x4 dacc[8];
#pragma unroll
    for (int ct = 0; ct < 8; ++ct) {
        half4 bfrag;
#pragma unroll
        for (int jj = 0; jj < 4; ++jj)
            bfrag[jj] = (_Float16)W2[(q * 4 + jj) * 128 + ct * 16 + nl];
        f32x4 z = {0.f, 0.f, 0.f, 0.f};
        dacc[ct] = __builtin_amdgcn_mfma_f32_16x16x16f16(afrag, bfrag, z, 0, 0, 0);
    }

    float bias[8];
#pragma unroll
    for (int ct = 0; ct < 8; ++ct) bias[ct] = b2[ct * 16 + nl];

    int rbase = base + q * 4;
#pragma unroll
    for (int i = 0; i < 4; ++i) {
        int r = rbase + i;
        if (r < N) {
            float* orow = out + (size_t)r * 128 + nl;
#pragma unroll
            for (int ct = 0; ct < 8; ++ct)
                __builtin_nontemporal_store(dacc[ct][i] + bias[ct], orow + ct * 16);
        }
    }
}

// ---------------- launch ----------------

extern "C" void kernel_launch(void* const* d_in, const int* in_sizes, int n_in,
                              void* d_out, int out_size, void* d_ws, size_t ws_size,
                              hipStream_t stream) {
    const float* x  = (const float*)d_in[0];
    const int*   ei = (const int*)d_in[1];
    const float* W1 = (const float*)d_in[2];
    const float* b1 = (const float*)d_in[3];
    const float* W2 = (const float*)d_in[4];
    const float* b2 = (const float*)d_in[5];
    float* out = (float*)d_out;

    const int N = in_sizes[0] / 128;
    const int E = in_sizes[1] / 2;
    const int* src = ei;
    const int* dst = ei + E;
    const int NB = (N + RANGE - 1) / RANGE;

    // ws (4B units): [pairbuf NB*CAP][gcursor NB][bbase NB+1][rowptr N+1][eidx E][dinv N][g1 8N][g2 8N]
    unsigned* pairbuf = (unsigned*)d_ws;
    int* gcursor = (int*)(pairbuf + (size_t)NB * CAP);
    int* bbase   = gcursor + NB;
    int* rowptr  = bbase + (NB + 1);
    int* eidx    = rowptr + (N + 1);
    float* dinv  = (float*)(eidx + E);
    __half* g1 = (__half*)(dinv + N);
    __half* g2 = g1 + 16 * N;

    const int B = 256;
    init_gcursor<<<1, B, 0, stream>>>(gcursor, NB);
    binpass<<<(E + T_TILE - 1) / T_TILE, B, 0, stream>>>(src, dst, E, gcursor, pairbuf);
    bucketscan<<<1, B, 0, stream>>>(gcursor, NB, bbase, rowptr, N);
    bucket_build<<<NB, 512, 0, stream>>>(pairbuf, gcursor, bbase, N, rowptr, dinv, eidx);
    gemm1_mfma<<<(N + 63) / 64, B, 0, stream>>>(x, W1, dinv, g1, N);
    gather1_kernel<<<(N * 4 + B - 1) / B, B, 0, stream>>>(rowptr, eidx, g1, dinv, b1, g2, N);
    gather2_gemm2<<<(N * 4 + B - 1) / B, B, 0, stream>>>(rowptr, eidx, g2, dinv, W2, b2, out, N);
}

// Round 12
// 151.138 us; speedup vs baseline: 1.3109x; 1.3109x over previous
//
#include <hip/hip_runtime.h>
#include <hip/hip_fp16.h>

typedef _Float16 half8 __attribute__((ext_vector_type(8)));
typedef _Float16 half4 __attribute__((ext_vector_type(4)));
typedef float f32x4 __attribute__((ext_vector_type(4)));

// ---------- binned CSR build ----------
#define RANGE    512
#define RSH      9
#define CAP      17408          // mean E/NB=16327 + 8 sigma
#define T_TILE   4096           // edges per binpass block (256 thr x 16)

__global__ void init_gcursor(int* __restrict__ gcursor, int NB) {
    int t = blockIdx.x * blockDim.x + threadIdx.x;
    if (t < NB) gcursor[t] = t * CAP;
}

__global__ __launch_bounds__(256) void binpass(const int* __restrict__ src,
                                               const int* __restrict__ dst, int E,
                                               int* __restrict__ gcursor,
                                               unsigned* __restrict__ pairbuf) {
    __shared__ unsigned sbuf[T_TILE];
    __shared__ unsigned char sbk[T_TILE];
    __shared__ int lcount[256], loff[256], lplace[256], gbase[256];
    int t = threadIdx.x;
    int base = blockIdx.x * T_TILE;
    int ecount = min(T_TILE, E - base);

    lcount[t] = 0;
    __syncthreads();

    unsigned pk[16];
    int bn[16];
#pragma unroll
    for (int k = 0; k < 16; ++k) {
        int i = base + t + k * 256;
        if (i < E) {
            int s = src[i], d = dst[i];
            bn[k] = d >> RSH;
            pk[k] = ((unsigned)s << RSH) | (unsigned)(d & (RANGE - 1));
            atomicAdd(&lcount[bn[k]], 1);
        } else bn[k] = -1;
    }
    __syncthreads();
    loff[t] = lcount[t];
    __syncthreads();
    for (int off = 1; off < 256; off <<= 1) {
        int u = (t >= off) ? loff[t - off] : 0;
        __syncthreads();
        loff[t] += u;
        __syncthreads();
    }
    int ex = loff[t] - lcount[t];
    __syncthreads();
    loff[t] = ex;
    lplace[t] = ex;
    if (lcount[t] > 0) gbase[t] = atomicAdd(&gcursor[t], lcount[t]);
    __syncthreads();
#pragma unroll
    for (int k = 0; k < 16; ++k) {
        if (bn[k] >= 0) {
            int pos = atomicAdd(&lplace[bn[k]], 1);
            sbuf[pos] = pk[k];
            sbk[pos] = (unsigned char)bn[k];
        }
    }
    __syncthreads();
    for (int i = t; i < ecount; i += 256) {
        int b = sbk[i];
        pairbuf[gbase[b] + (i - loff[b])] = sbuf[i];
    }
}

__global__ __launch_bounds__(256) void bucketscan(const int* __restrict__ gcursor, int NB,
                                                  int* __restrict__ bbase,
                                                  int* __restrict__ rowptr, int N) {
    __shared__ int sd[256];
    int t = threadIdx.x;
    int c = (t < NB) ? (gcursor[t] - t * CAP) : 0;
    sd[t] = c;
    __syncthreads();
    for (int off = 1; off < 256; off <<= 1) {
        int u = (t >= off) ? sd[t - off] : 0;
        __syncthreads();
        sd[t] += u;
        __syncthreads();
    }
    if (t < NB) bbase[t] = sd[t] - c;
    if (t == 255) { bbase[NB] = sd[255]; rowptr[N] = sd[255]; }
}

__global__ __launch_bounds__(512) void bucket_build(const unsigned* __restrict__ pairbuf,
                                                    const int* __restrict__ gcursor,
                                                    const int* __restrict__ bbase, int N,
                                                    int* __restrict__ rowptr,
                                                    float* __restrict__ dinv,
                                                    int* __restrict__ eidx) {
    __shared__ int lcnt[RANGE];
    __shared__ int lsc[RANGE];
    int b = blockIdx.x, t = threadIdx.x;
    int cnt = gcursor[b] - b * CAP;
    const unsigned* pb = pairbuf + (size_t)b * CAP;

    lcnt[t] = 0;
    __syncthreads();
    for (int i = t; i < cnt; i += 512) atomicAdd(&lcnt[pb[i] & (RANGE - 1)], 1);
    __syncthreads();
    lsc[t] = lcnt[t];
    __syncthreads();
    for (int off = 1; off < 512; off <<= 1) {
        int u = (t >= off) ? lsc[t - off] : 0;
        __syncthreads();
        lsc[t] += u;
        __syncthreads();
    }
    int ex = lsc[t] - lcnt[t];
    int gb = bbase[b];
    int node = b * RANGE + t;
    if (node < N) {
        rowptr[node] = gb + ex;
        dinv[node] = rsqrtf((float)lcnt[t] + 1.0f);
    }
    __syncthreads();
    lsc[t] = gb + ex;
    __syncthreads();
    for (int i = t; i < cnt; i += 512) {
        unsigned p = pb[i];
        int pos = atomicAdd(&lsc[p & (RANGE - 1)], 1);
        eidx[pos] = (int)(p >> RSH);
    }
}

// ---------------- GEMM1 via MFMA: g1 = fp16((x @ W1) * dinv[row]) ----------------

__global__ __launch_bounds__(256) void gemm1_mfma(const float* __restrict__ x,
                                                  const float* __restrict__ W1,
                                                  const float* __restrict__ dinv,
                                                  __half* __restrict__ g1, int N) {
    int wave = threadIdx.x >> 6;
    int lane = threadIdx.x & 63;
    int R0 = blockIdx.x * 64 + wave * 16;
    if (R0 >= N) return;
    int m = lane & 15;
    int kb = (lane >> 4) * 8;
    int row = R0 + m;
    int rowc = min(row, N - 1);

    half8 bfrag[4];
#pragma unroll
    for (int kk = 0; kk < 4; ++kk) {
#pragma unroll
        for (int j = 0; j < 8; ++j)
            bfrag[kk][j] = (_Float16)W1[(kk * 32 + kb + j) * 16 + m];
    }

    const float* xr = x + (size_t)rowc * 128;
    float4 u[8];
#pragma unroll
    for (int kk = 0; kk < 4; ++kk) {
        u[2 * kk]     = *reinterpret_cast<const float4*>(xr + kk * 32 + kb);
        u[2 * kk + 1] = *reinterpret_cast<const float4*>(xr + kk * 32 + kb + 4);
    }

    f32x4 acc = {0.f, 0.f, 0.f, 0.f};
#pragma unroll
    for (int kk = 0; kk < 4; ++kk) {
        half8 a;
        a[0] = (_Float16)u[2 * kk].x;     a[1] = (_Float16)u[2 * kk].y;
        a[2] = (_Float16)u[2 * kk].z;     a[3] = (_Float16)u[2 * kk].w;
        a[4] = (_Float16)u[2 * kk + 1].x; a[5] = (_Float16)u[2 * kk + 1].y;
        a[6] = (_Float16)u[2 * kk + 1].z; a[7] = (_Float16)u[2 * kk + 1].w;
        acc = __builtin_amdgcn_mfma_f32_16x16x32_f16(a, bfrag[kk], acc, 0, 0, 0);
    }

#pragma unroll
    for (int i = 0; i < 4; ++i) {
        int r = R0 + (lane >> 4) * 4 + i;
        if (r < N) g1[(size_t)r * 16 + m] = __float2half(acc[i] * dinv[r]);
    }
}

// ---------------- gather1: lane = (node, quarter); unroll-8 for MLP ----------------

__global__ __launch_bounds__(256) void gather1_kernel(const int* __restrict__ rowptr,
                                                      const int* __restrict__ eidx,
                                                      const __half* __restrict__ g1,
                                                      const float* __restrict__ dinv,
                                                      const float* __restrict__ b1,
                                                      __half* __restrict__ g2, int N) {
    int gid = blockIdx.x * blockDim.x + threadIdx.x;
    int lane = threadIdx.x & 63;
    int q = lane & 3;
    int d = gid >> 2;
    if (d >= N) return;
    int lo = rowptr[d], hi = rowptr[d + 1];
    float a0 = 0, a1 = 0, a2 = 0, a3 = 0;
    int j = lo;
    for (; j + 7 < hi; j += 8) {
        int s[8];
#pragma unroll
        for (int k = 0; k < 8; ++k) s[k] = eidx[j + k];
        uint2 v[8];
#pragma unroll
        for (int k = 0; k < 8; ++k)
            v[k] = *reinterpret_cast<const uint2*>(g1 + s[k] * 16 + q * 4);
#pragma unroll
        for (int k = 0; k < 8; ++k) {
            float2 p0 = __half22float2(*reinterpret_cast<__half2*>(&v[k].x));
            float2 p1 = __half22float2(*reinterpret_cast<__half2*>(&v[k].y));
            a0 += p0.x; a1 += p0.y; a2 += p1.x; a3 += p1.y;
        }
    }
    for (; j < hi; ++j) {
        int s = eidx[j];
        uint2 v = *reinterpret_cast<const uint2*>(g1 + s * 16 + q * 4);
        float2 p0 = __half22float2(*reinterpret_cast<__half2*>(&v.x));
        float2 p1 = __half22float2(*reinterpret_cast<__half2*>(&v.y));
        a0 += p0.x; a1 += p0.y; a2 += p1.x; a3 += p1.y;
    }
    float di = dinv[d];
    uint2 sv = *reinterpret_cast<const uint2*>(g1 + d * 16 + q * 4);
    float2 sf0 = __half22float2(*reinterpret_cast<__half2*>(&sv.x));
    float2 sf1 = __half22float2(*reinterpret_cast<__half2*>(&sv.y));
    float4 bb = *reinterpret_cast<const float4*>(b1 + q * 4);
    float o0 = fmaxf(di * (a0 + sf0.x) + bb.x, 0.0f) * di;
    float o1 = fmaxf(di * (a1 + sf0.y) + bb.y, 0.0f) * di;
    float o2 = fmaxf(di * (a2 + sf1.x) + bb.z, 0.0f) * di;
    float o3 = fmaxf(di * (a3 + sf1.y) + bb.w, 0.0f) * di;
    __half2 w0 = __floats2half2_rn(o0, o1);
    __half2 w1 = __floats2half2_rn(o2, o3);
    uint2 wv;
    wv.x = *reinterpret_cast<unsigned*>(&w0);
    wv.y = *reinterpret_cast<unsigned*>(&w1);
    *reinterpret_cast<uint2*>(g2 + d * 16 + q * 4) = wv;
}

// ---------------- fused gather2 + GEMM2 (R10 layout, unroll-8) ----------------
// wave = 16 nodes. lane l -> node base+(l&15), feature quarter q=l>>4.
// After accumulation lane l holds the mfma_f32_16x16x16_f16 A-fragment.
// D layout: col=lane&15, row=(lane>>4)*4+reg.

__global__ __launch_bounds__(256) void gather2_gemm2(const int* __restrict__ rowptr,
                                                     const int* __restrict__ eidx,
                                                     const __half* __restrict__ g2,
                                                     const float* __restrict__ dinv,
                                                     const float* __restrict__ W2,
                                                     const float* __restrict__ b2,
                                                     float* __restrict__ out, int N) {
    int gid = blockIdx.x * blockDim.x + threadIdx.x;
    int wid = gid >> 6;
    int lane = threadIdx.x & 63;
    int base = wid * 16;
    if (base >= N) return;
    int nl = lane & 15;
    int q = lane >> 4;
    int d = base + nl;
    int dc = min(d, N - 1);
    int lo = rowptr[dc], hi = rowptr[dc + 1];

    float a0 = 0, a1 = 0, a2 = 0, a3 = 0;
    int j = lo;
    for (; j + 7 < hi; j += 8) {
        int s[8];
#pragma unroll
        for (int k = 0; k < 8; ++k) s[k] = eidx[j + k];
        uint2 v[8];
#pragma unroll
        for (int k = 0; k < 8; ++k)
            v[k] = *reinterpret_cast<const uint2*>(g2 + s[k] * 16 + q * 4);
#pragma unroll
        for (int k = 0; k < 8; ++k) {
            float2 p0 = __half22float2(*reinterpret_cast<__half2*>(&v[k].x));
            float2 p1 = __half22float2(*reinterpret_cast<__half2*>(&v[k].y));
            a0 += p0.x; a1 += p0.y; a2 += p1.x; a3 += p1.y;
        }
    }
    for (; j < hi; ++j) {
        int s = eidx[j];
        uint2 v = *reinterpret_cast<const uint2*>(g2 + s * 16 + q * 4);
        float2 p0 = __half22float2(*reinterpret_cast<__half2*>(&v.x));
        float2 p1 = __half22float2(*reinterpret_cast<__half2*>(&v.y));
        a0 += p0.x; a1 += p0.y; a2 += p1.x; a3 += p1.y;
    }

    // self-loop + dinv -> A fragment (fp16)
    float di = dinv[dc];
    uint2 sv = *reinterpret_cast<const uint2*>(g2 + dc * 16 + q * 4);
    float2 sf0 = __half22float2(*reinterpret_cast<__half2*>(&sv.x));
    float2 sf1 = __half22float2(*reinterpret_cast<__half2*>(&sv.y));
    half4 afrag;
    afrag[0] = (_Float16)(di * (a0 + sf0.x));
    afrag[1] = (_Float16)(di * (a1 + sf0.y));
    afrag[2] = (_Float16)(di * (a2 + sf1.x));
    afrag[3] = (_Float16)(di * (a3 + sf1.y));

    // 8 MFMAs over W2 column tiles
    f32x4 dacc[8];
#pragma unroll
    for (int ct = 0; ct < 8; ++ct) {
        half4 bfrag;
#pragma unroll
        for (int jj = 0; jj < 4; ++jj)
            bfrag[jj] = (_Float16)W2[(q * 4 + jj) * 128 + ct * 16 + nl];
        f32x4 z = {0.f, 0.f, 0.f, 0.f};
        dacc[ct] = __builtin_amdgcn_mfma_f32_16x16x16f16(afrag, bfrag, z, 0, 0, 0);
    }

    float bias[8];
#pragma unroll
    for (int ct = 0; ct < 8; ++ct) bias[ct] = b2[ct * 16 + nl];

    int rbase = base + q * 4;
#pragma unroll
    for (int i = 0; i < 4; ++i) {
        int r = rbase + i;
        if (r < N) {
            float* orow = out + (size_t)r * 128 + nl;
#pragma unroll
            for (int ct = 0; ct < 8; ++ct) orow[ct * 16] = dacc[ct][i] + bias[ct];
        }
    }
}

// ---------------- launch ----------------

extern "C" void kernel_launch(void* const* d_in, const int* in_sizes, int n_in,
                              void* d_out, int out_size, void* d_ws, size_t ws_size,
                              hipStream_t stream) {
    const float* x  = (const float*)d_in[0];
    const int*   ei = (const int*)d_in[1];
    const float* W1 = (const float*)d_in[2];
    const float* b1 = (const float*)d_in[3];
    const float* W2 = (const float*)d_in[4];
    const float* b2 = (const float*)d_in[5];
    float* out = (float*)d_out;

    const int N = in_sizes[0] / 128;
    const int E = in_sizes[1] / 2;
    const int* src = ei;
    const int* dst = ei + E;
    const int NB = (N + RANGE - 1) / RANGE;

    // ws (4B units): [pairbuf NB*CAP][gcursor NB][bbase NB+1][rowptr N+1][eidx E][dinv N][g1 8N][g2 8N]
    unsigned* pairbuf = (unsigned*)d_ws;
    int* gcursor = (int*)(pairbuf + (size_t)NB * CAP);
    int* bbase   = gcursor + NB;
    int* rowptr  = bbase + (NB + 1);
    int* eidx    = rowptr + (N + 1);
    float* dinv  = (float*)(eidx + E);
    __half* g1 = (__half*)(dinv + N);
    __half* g2 = g1 + 16 * N;

    const int B = 256;
    init_gcursor<<<1, B, 0, stream>>>(gcursor, NB);
    binpass<<<(E + T_TILE - 1) / T_TILE, B, 0, stream>>>(src, dst, E, gcursor, pairbuf);
    bucketscan<<<1, B, 0, stream>>>(gcursor, NB, bbase, rowptr, N);
    bucket_build<<<NB, 512, 0, stream>>>(pairbuf, gcursor, bbase, N, rowptr, dinv, eidx);
    gemm1_mfma<<<(N + 63) / 64, B, 0, stream>>>(x, W1, dinv, g1, N);
    gather1_kernel<<<(N * 4 + B - 1) / B, B, 0, stream>>>(rowptr, eidx, g1, dinv, b1, g2, N);
    gather2_gemm2<<<(N * 4 + B - 1) / B, B, 0, stream>>>(rowptr, eidx, g2, dinv, W2, b2, out, N);
}

// Round 13
// 148.258 us; speedup vs baseline: 1.3364x; 1.0194x over previous
//
#include <hip/hip_runtime.h>
#include <hip/hip_fp16.h>

typedef _Float16 half8 __attribute__((ext_vector_type(8)));
typedef _Float16 half4 __attribute__((ext_vector_type(4)));
typedef float f32x4 __attribute__((ext_vector_type(4)));
typedef unsigned uint4v __attribute__((ext_vector_type(4)));

// ---------- binned CSR build ----------
#define RANGE    512
#define RSH      9
#define CAP      17408          // mean E/NB=16327 + 8 sigma
#define T_TILE   4096           // edges per binpass block (256 thr x 16)

__global__ void init_gcursor(int* __restrict__ gcursor, int NB) {
    int t = blockIdx.x * blockDim.x + threadIdx.x;
    if (t < NB) gcursor[t] = t * CAP;
}

__global__ __launch_bounds__(256) void binpass(const int* __restrict__ src,
                                               const int* __restrict__ dst, int E,
                                               int* __restrict__ gcursor,
                                               unsigned* __restrict__ pairbuf) {
    __shared__ unsigned sbuf[T_TILE];
    __shared__ unsigned char sbk[T_TILE];
    __shared__ int lcount[256], loff[256], lplace[256], gbase[256];
    int t = threadIdx.x;
    int base = blockIdx.x * T_TILE;
    int ecount = min(T_TILE, E - base);

    lcount[t] = 0;
    __syncthreads();

    unsigned pk[16];
    int bn[16];
#pragma unroll
    for (int k = 0; k < 16; ++k) {
        int i = base + t + k * 256;
        if (i < E) {
            int s = src[i], d = dst[i];
            bn[k] = d >> RSH;
            pk[k] = ((unsigned)s << RSH) | (unsigned)(d & (RANGE - 1));
            atomicAdd(&lcount[bn[k]], 1);
        } else bn[k] = -1;
    }
    __syncthreads();
    loff[t] = lcount[t];
    __syncthreads();
    for (int off = 1; off < 256; off <<= 1) {
        int u = (t >= off) ? loff[t - off] : 0;
        __syncthreads();
        loff[t] += u;
        __syncthreads();
    }
    int ex = loff[t] - lcount[t];
    __syncthreads();
    loff[t] = ex;
    lplace[t] = ex;
    if (lcount[t] > 0) gbase[t] = atomicAdd(&gcursor[t], lcount[t]);
    __syncthreads();
#pragma unroll
    for (int k = 0; k < 16; ++k) {
        if (bn[k] >= 0) {
            int pos = atomicAdd(&lplace[bn[k]], 1);
            sbuf[pos] = pk[k];
            sbk[pos] = (unsigned char)bn[k];
        }
    }
    __syncthreads();
    for (int i = t; i < ecount; i += 256) {
        int b = sbk[i];
        pairbuf[gbase[b] + (i - loff[b])] = sbuf[i];
    }
}

__global__ __launch_bounds__(256) void bucketscan(const int* __restrict__ gcursor, int NB,
                                                  int* __restrict__ bbase,
                                                  int* __restrict__ rowptr, int N) {
    __shared__ int sd[256];
    int t = threadIdx.x;
    int c = (t < NB) ? (gcursor[t] - t * CAP) : 0;
    sd[t] = c;
    __syncthreads();
    for (int off = 1; off < 256; off <<= 1) {
        int u = (t >= off) ? sd[t - off] : 0;
        __syncthreads();
        sd[t] += u;
        __syncthreads();
    }
    if (t < NB) bbase[t] = sd[t] - c;
    if (t == 255) { bbase[NB] = sd[255]; rowptr[N] = sd[255]; }
}

__global__ __launch_bounds__(512) void bucket_build(const unsigned* __restrict__ pairbuf,
                                                    const int* __restrict__ gcursor,
                                                    const int* __restrict__ bbase, int N,
                                                    int* __restrict__ rowptr,
                                                    float* __restrict__ dinv,
                                                    int* __restrict__ eidx) {
    __shared__ int lcnt[RANGE];
    __shared__ int lsc[RANGE];
    int b = blockIdx.x, t = threadIdx.x;
    int cnt = gcursor[b] - b * CAP;
    const unsigned* pb = pairbuf + (size_t)b * CAP;

    lcnt[t] = 0;
    __syncthreads();
    for (int i = t; i < cnt; i += 512) atomicAdd(&lcnt[pb[i] & (RANGE - 1)], 1);
    __syncthreads();
    lsc[t] = lcnt[t];
    __syncthreads();
    for (int off = 1; off < 512; off <<= 1) {
        int u = (t >= off) ? lsc[t - off] : 0;
        __syncthreads();
        lsc[t] += u;
        __syncthreads();
    }
    int ex = lsc[t] - lcnt[t];
    int gb = bbase[b];
    int node = b * RANGE + t;
    if (node < N) {
        rowptr[node] = gb + ex;
        dinv[node] = rsqrtf((float)lcnt[t] + 1.0f);
    }
    __syncthreads();
    lsc[t] = gb + ex;
    __syncthreads();
    for (int i = t; i < cnt; i += 512) {
        unsigned p = pb[i];
        int pos = atomicAdd(&lsc[p & (RANGE - 1)], 1);
        eidx[pos] = (int)(p >> RSH);
    }
}

// ---------- helpers ----------

__device__ __forceinline__ void unp8(uint4v v, float* f) {
#pragma unroll
    for (int k = 0; k < 4; ++k) {
        unsigned w = v[k];
        __half2 h2 = *reinterpret_cast<__half2*>(&w);
        float2 t = __half22float2(h2);
        f[2 * k] = t.x; f[2 * k + 1] = t.y;
    }
}

__device__ __forceinline__ void acc8(float* a, uint4v v) {
#pragma unroll
    for (int k = 0; k < 4; ++k) {
        unsigned w = v[k];
        __half2 h2 = *reinterpret_cast<__half2*>(&w);
        float2 t = __half22float2(h2);
        a[2 * k]     += t.x;
        a[2 * k + 1] += t.y;
    }
}

__device__ __forceinline__ uint4v pk8(const float* o) {
    uint4v r;
#pragma unroll
    for (int k = 0; k < 4; ++k) {
        __half2 h2 = __floats2half2_rn(o[2 * k], o[2 * k + 1]);
        r[k] = *reinterpret_cast<unsigned*>(&h2);
    }
    return r;
}

// ---------------- GEMM1 via MFMA: g1 = fp16((x @ W1) * dinv[row]) ----------------

__global__ __launch_bounds__(256) void gemm1_mfma(const float* __restrict__ x,
                                                  const float* __restrict__ W1,
                                                  const float* __restrict__ dinv,
                                                  __half* __restrict__ g1, int N) {
    int wave = threadIdx.x >> 6;
    int lane = threadIdx.x & 63;
    int R0 = blockIdx.x * 64 + wave * 16;
    if (R0 >= N) return;
    int m = lane & 15;
    int kb = (lane >> 4) * 8;
    int row = R0 + m;
    int rowc = min(row, N - 1);

    half8 bfrag[4];
#pragma unroll
    for (int kk = 0; kk < 4; ++kk) {
#pragma unroll
        for (int j = 0; j < 8; ++j)
            bfrag[kk][j] = (_Float16)W1[(kk * 32 + kb + j) * 16 + m];
    }

    const float* xr = x + (size_t)rowc * 128;
    float4 u[8];
#pragma unroll
    for (int kk = 0; kk < 4; ++kk) {
        u[2 * kk]     = *reinterpret_cast<const float4*>(xr + kk * 32 + kb);
        u[2 * kk + 1] = *reinterpret_cast<const float4*>(xr + kk * 32 + kb + 4);
    }

    f32x4 acc = {0.f, 0.f, 0.f, 0.f};
#pragma unroll
    for (int kk = 0; kk < 4; ++kk) {
        half8 a;
        a[0] = (_Float16)u[2 * kk].x;     a[1] = (_Float16)u[2 * kk].y;
        a[2] = (_Float16)u[2 * kk].z;     a[3] = (_Float16)u[2 * kk].w;
        a[4] = (_Float16)u[2 * kk + 1].x; a[5] = (_Float16)u[2 * kk + 1].y;
        a[6] = (_Float16)u[2 * kk + 1].z; a[7] = (_Float16)u[2 * kk + 1].w;
        acc = __builtin_amdgcn_mfma_f32_16x16x32_f16(a, bfrag[kk], acc, 0, 0, 0);
    }

#pragma unroll
    for (int i = 0; i < 4; ++i) {
        int r = R0 + (lane >> 4) * 4 + i;
        if (r < N) g1[(size_t)r * 16 + m] = __float2half(acc[i] * dinv[r]);
    }
}

// ---------------- gather1: lane = (node, h, es); uint4 loads, unroll-8 ----------------
// sub = lane&3: h = sub&1 (feature half), es = sub>>1 (edge slot).
// Each lane: 8 independent uint4 (16B) loads per iteration = 8 edges of its slot.

__global__ __launch_bounds__(256) void gather1_kernel(const int* __restrict__ rowptr,
                                                      const int* __restrict__ eidx,
                                                      const __half* __restrict__ g1,
                                                      const float* __restrict__ dinv,
                                                      const float* __restrict__ b1,
                                                      __half* __restrict__ g2, int N) {
    int gid = blockIdx.x * blockDim.x + threadIdx.x;
    int d = gid >> 2;
    if (d >= N) return;
    int sub = threadIdx.x & 3;
    int h = sub & 1, es = sub >> 1;
    int f0 = h * 8;
    int lo = rowptr[d], hi = rowptr[d + 1];
    float a[8] = {0, 0, 0, 0, 0, 0, 0, 0};
    int j = lo + es;
    for (; j + 14 < hi; j += 16) {
        int s[8];
#pragma unroll
        for (int k = 0; k < 8; ++k) s[k] = eidx[j + 2 * k];
        uint4v v[8];
#pragma unroll
        for (int k = 0; k < 8; ++k)
            v[k] = *reinterpret_cast<const uint4v*>(g1 + s[k] * 16 + f0);
#pragma unroll
        for (int k = 0; k < 8; ++k) acc8(a, v[k]);
    }
    for (; j < hi; j += 2) {
        int s = eidx[j];
        uint4v v = *reinterpret_cast<const uint4v*>(g1 + s * 16 + f0);
        acc8(a, v);
    }
#pragma unroll
    for (int k = 0; k < 8; ++k) a[k] += __shfl_xor(a[k], 2);
    if (es == 0) {
        float di = dinv[d];
        uint4v sv = *reinterpret_cast<const uint4v*>(g1 + d * 16 + f0);
        float sf[8];
        unp8(sv, sf);
        f32x4 bb0 = *reinterpret_cast<const f32x4*>(b1 + f0);
        f32x4 bb1 = *reinterpret_cast<const f32x4*>(b1 + f0 + 4);
        float o[8];
#pragma unroll
        for (int k = 0; k < 4; ++k) {
            o[k]     = fmaxf(di * (a[k] + sf[k]) + bb0[k], 0.0f) * di;
            o[k + 4] = fmaxf(di * (a[k + 4] + sf[k + 4]) + bb1[k], 0.0f) * di;
        }
        *reinterpret_cast<uint4v*>(g2 + d * 16 + f0) = pk8(o);
    }
}

// ---------------- fused gather2 + GEMM2: (node, es@bit4, h@bit5), uint4, unroll-8 ----------------
// lane = h*32 + es*16 + nl. After shfl_xor(16) both es-slots merged; lane q=lane>>4=(h<<1|es)
// needs feats q*4..q*4+3 of half q>>1 = h -> select hi4=es*4 from its own half. MFMA as R10.

__global__ __launch_bounds__(256) void gather2_gemm2(const int* __restrict__ rowptr,
                                                     const int* __restrict__ eidx,
                                                     const __half* __restrict__ g2,
                                                     const float* __restrict__ dinv,
                                                     const float* __restrict__ W2,
                                                     const float* __restrict__ b2,
                                                     float* __restrict__ out, int N) {
    int gid = blockIdx.x * blockDim.x + threadIdx.x;
    int wid = gid >> 6;
    int lane = threadIdx.x & 63;
    int base = wid * 16;
    if (base >= N) return;
    int nl = lane & 15;
    int q = lane >> 4;
    int es = q & 1;
    int h = lane >> 5;
    int f0 = h * 8;
    int d = base + nl;
    int dc = min(d, N - 1);
    int lo = rowptr[dc], hi = rowptr[dc + 1];

    float a[8] = {0, 0, 0, 0, 0, 0, 0, 0};
    int j = lo + es;
    for (; j + 14 < hi; j += 16) {
        int s[8];
#pragma unroll
        for (int k = 0; k < 8; ++k) s[k] = eidx[j + 2 * k];
        uint4v v[8];
#pragma unroll
        for (int k = 0; k < 8; ++k)
            v[k] = *reinterpret_cast<const uint4v*>(g2 + s[k] * 16 + f0);
#pragma unroll
        for (int k = 0; k < 8; ++k) acc8(a, v[k]);
    }
    for (; j < hi; j += 2) {
        int s = eidx[j];
        uint4v v = *reinterpret_cast<const uint4v*>(g2 + s * 16 + f0);
        acc8(a, v);
    }
#pragma unroll
    for (int k = 0; k < 8; ++k) a[k] += __shfl_xor(a[k], 16);

    float di = dinv[dc];
    uint4v sv = *reinterpret_cast<const uint4v*>(g2 + dc * 16 + f0);
    float sf[8];
    unp8(sv, sf);
    float af[8];
#pragma unroll
    for (int k = 0; k < 8; ++k) af[k] = di * (a[k] + sf[k]);

    int hi4 = es * 4;
    half4 afrag;
#pragma unroll
    for (int jj = 0; jj < 4; ++jj) afrag[jj] = (_Float16)af[hi4 + jj];

    f32x4 dacc[8];
#pragma unroll
    for (int ct = 0; ct < 8; ++ct) {
        half4 bfrag;
#pragma unroll
        for (int jj = 0; jj < 4; ++jj)
            bfrag[jj] = (_Float16)W2[(q * 4 + jj) * 128 + ct * 16 + nl];
        f32x4 z = {0.f, 0.f, 0.f, 0.f};
        dacc[ct] = __builtin_amdgcn_mfma_f32_16x16x16f16(afrag, bfrag, z, 0, 0, 0);
    }

    float bias[8];
#pragma unroll
    for (int ct = 0; ct < 8; ++ct) bias[ct] = b2[ct * 16 + nl];

    int rbase = base + q * 4;
#pragma unroll
    for (int i = 0; i < 4; ++i) {
        int r = rbase + i;
        if (r < N) {
            float* orow = out + (size_t)r * 128 + nl;
#pragma unroll
            for (int ct = 0; ct < 8; ++ct) orow[ct * 16] = dacc[ct][i] + bias[ct];
        }
    }
}

// ---------------- launch ----------------

extern "C" void kernel_launch(void* const* d_in, const int* in_sizes, int n_in,
                              void* d_out, int out_size, void* d_ws, size_t ws_size,
                              hipStream_t stream) {
    const float* x  = (const float*)d_in[0];
    const int*   ei = (const int*)d_in[1];
    const float* W1 = (const float*)d_in[2];
    const float* b1 = (const float*)d_in[3];
    const float* W2 = (const float*)d_in[4];
    const float* b2 = (const float*)d_in[5];
    float* out = (float*)d_out;

    const int N = in_sizes[0] / 128;
    const int E = in_sizes[1] / 2;
    const int* src = ei;
    const int* dst = ei + E;
    const int NB = (N + RANGE - 1) / RANGE;

    // ws (4B units): [pairbuf NB*CAP][gcursor NB][bbase NB+1][rowptr N+1][eidx E][dinv N][g1 8N][g2 8N]
    unsigned* pairbuf = (unsigned*)d_ws;
    int* gcursor = (int*)(pairbuf + (size_t)NB * CAP);
    int* bbase   = gcursor + NB;
    int* rowptr  = bbase + (NB + 1);
    int* eidx    = rowptr + (N + 1);
    float* dinv  = (float*)(eidx + E);
    __half* g1 = (__half*)(dinv + N);
    __half* g2 = g1 + 16 * N;

    const int B = 256;
    init_gcursor<<<1, B, 0, stream>>>(gcursor, NB);
    binpass<<<(E + T_TILE - 1) / T_TILE, B, 0, stream>>>(src, dst, E, gcursor, pairbuf);
    bucketscan<<<1, B, 0, stream>>>(gcursor, NB, bbase, rowptr, N);
    bucket_build<<<NB, 512, 0, stream>>>(pairbuf, gcursor, bbase, N, rowptr, dinv, eidx);
    gemm1_mfma<<<(N + 63) / 64, B, 0, stream>>>(x, W1, dinv, g1, N);
    gather1_kernel<<<(N * 4 + B - 1) / B, B, 0, stream>>>(rowptr, eidx, g1, dinv, b1, g2, N);
    gather2_gemm2<<<(N * 4 + B - 1) / B, B, 0, stream>>>(rowptr, eidx, g2, dinv, W2, b2, out, N);
}

// Round 14
// 142.632 us; speedup vs baseline: 1.3891x; 1.0394x over previous
//
#include <hip/hip_runtime.h>
#include <hip/hip_fp16.h>

typedef _Float16 half8 __attribute__((ext_vector_type(8)));
typedef _Float16 half4 __attribute__((ext_vector_type(4)));
typedef float f32x4 __attribute__((ext_vector_type(4)));
typedef unsigned uint4v __attribute__((ext_vector_type(4)));

// ---------- binned CSR build ----------
#define RANGE    512
#define RSH      9
#define CAP      17408          // mean E/NB=16327 + 8 sigma
#define T_TILE   4096           // edges per binpass block (256 thr x 16)

__global__ void init_gcursor(int* __restrict__ gcursor, int NB) {
    int t = blockIdx.x * blockDim.x + threadIdx.x;
    if (t < NB) gcursor[t] = t * CAP;
}

__global__ __launch_bounds__(256) void binpass(const int* __restrict__ src,
                                               const int* __restrict__ dst, int E,
                                               int* __restrict__ gcursor,
                                               unsigned* __restrict__ pairbuf) {
    __shared__ unsigned sbuf[T_TILE];
    __shared__ unsigned char sbk[T_TILE];
    __shared__ int lcount[256], loff[256], lplace[256], gbase[256];
    int t = threadIdx.x;
    int base = blockIdx.x * T_TILE;
    int ecount = min(T_TILE, E - base);

    lcount[t] = 0;
    __syncthreads();

    unsigned pk[16];
    int bn[16];
#pragma unroll
    for (int k4 = 0; k4 < 4; ++k4) {
        int i = base + (t + k4 * 256) * 4;
        if (i + 3 < E) {
            int4 sv = *reinterpret_cast<const int4*>(src + i);
            int4 dv = *reinterpret_cast<const int4*>(dst + i);
            int ss[4] = {sv.x, sv.y, sv.z, sv.w};
            int dd[4] = {dv.x, dv.y, dv.z, dv.w};
#pragma unroll
            for (int m = 0; m < 4; ++m) {
                int k = k4 * 4 + m;
                bn[k] = dd[m] >> RSH;
                pk[k] = ((unsigned)ss[m] << RSH) | (unsigned)(dd[m] & (RANGE - 1));
                atomicAdd(&lcount[bn[k]], 1);
            }
        } else {
#pragma unroll
            for (int m = 0; m < 4; ++m) {
                int k = k4 * 4 + m;
                int ii = i + m;
                if (ii < E) {
                    int s = src[ii], d = dst[ii];
                    bn[k] = d >> RSH;
                    pk[k] = ((unsigned)s << RSH) | (unsigned)(d & (RANGE - 1));
                    atomicAdd(&lcount[bn[k]], 1);
                } else bn[k] = -1;
            }
        }
    }
    __syncthreads();
    loff[t] = lcount[t];
    __syncthreads();
    for (int off = 1; off < 256; off <<= 1) {
        int u = (t >= off) ? loff[t - off] : 0;
        __syncthreads();
        loff[t] += u;
        __syncthreads();
    }
    int ex = loff[t] - lcount[t];
    __syncthreads();
    loff[t] = ex;
    lplace[t] = ex;
    if (lcount[t] > 0) gbase[t] = atomicAdd(&gcursor[t], lcount[t]);
    __syncthreads();
#pragma unroll
    for (int k = 0; k < 16; ++k) {
        if (bn[k] >= 0) {
            int pos = atomicAdd(&lplace[bn[k]], 1);
            sbuf[pos] = pk[k];
            sbk[pos] = (unsigned char)bn[k];
        }
    }
    __syncthreads();
    for (int i = t; i < ecount; i += 256) {
        int b = sbk[i];
        pairbuf[gbase[b] + (i - loff[b])] = sbuf[i];
    }
}

__global__ __launch_bounds__(256) void bucketscan(const int* __restrict__ gcursor, int NB,
                                                  int* __restrict__ bbase,
                                                  int* __restrict__ rowptr, int N) {
    __shared__ int sd[256];
    int t = threadIdx.x;
    int c = (t < NB) ? (gcursor[t] - t * CAP) : 0;
    sd[t] = c;
    __syncthreads();
    for (int off = 1; off < 256; off <<= 1) {
        int u = (t >= off) ? sd[t - off] : 0;
        __syncthreads();
        sd[t] += u;
        __syncthreads();
    }
    if (t < NB) bbase[t] = sd[t] - c;
    if (t == 255) { bbase[NB] = sd[255]; rowptr[N] = sd[255]; }
}

__global__ __launch_bounds__(512) void bucket_build(const unsigned* __restrict__ pairbuf,
                                                    const int* __restrict__ gcursor,
                                                    const int* __restrict__ bbase, int N,
                                                    int* __restrict__ rowptr,
                                                    float* __restrict__ dinv,
                                                    int* __restrict__ eidx) {
    __shared__ int lcnt[RANGE];
    __shared__ int lsc[RANGE];
    int b = blockIdx.x, t = threadIdx.x;
    int cnt = gcursor[b] - b * CAP;
    const unsigned* pb = pairbuf + (size_t)b * CAP;

    lcnt[t] = 0;
    __syncthreads();
    for (int i = t; i < cnt; i += 512) atomicAdd(&lcnt[pb[i] & (RANGE - 1)], 1);
    __syncthreads();
    lsc[t] = lcnt[t];
    __syncthreads();
    for (int off = 1; off < 512; off <<= 1) {
        int u = (t >= off) ? lsc[t - off] : 0;
        __syncthreads();
        lsc[t] += u;
        __syncthreads();
    }
    int ex = lsc[t] - lcnt[t];
    int gb = bbase[b];
    int node = b * RANGE + t;
    if (node < N) {
        rowptr[node] = gb + ex;
        dinv[node] = rsqrtf((float)lcnt[t] + 1.0f);
    }
    __syncthreads();
    lsc[t] = gb + ex;
    __syncthreads();
    for (int i = t; i < cnt; i += 512) {
        unsigned p = pb[i];
        int pos = atomicAdd(&lsc[p & (RANGE - 1)], 1);
        eidx[pos] = (int)(p >> RSH);
    }
}

// ---------- helpers ----------

__device__ __forceinline__ void unp8(uint4v v, float* f) {
#pragma unroll
    for (int k = 0; k < 4; ++k) {
        unsigned w = v[k];
        __half2 h2 = *reinterpret_cast<__half2*>(&w);
        float2 t = __half22float2(h2);
        f[2 * k] = t.x; f[2 * k + 1] = t.y;
    }
}

__device__ __forceinline__ void acc8(float* a, uint4v v) {
#pragma unroll
    for (int k = 0; k < 4; ++k) {
        unsigned w = v[k];
        __half2 h2 = *reinterpret_cast<__half2*>(&w);
        float2 t = __half22float2(h2);
        a[2 * k]     += t.x;
        a[2 * k + 1] += t.y;
    }
}

__device__ __forceinline__ uint4v pk8(const float* o) {
    uint4v r;
#pragma unroll
    for (int k = 0; k < 4; ++k) {
        __half2 h2 = __floats2half2_rn(o[2 * k], o[2 * k + 1]);
        r[k] = *reinterpret_cast<unsigned*>(&h2);
    }
    return r;
}

// ---------------- GEMM1 via MFMA: g1 = fp16((x @ W1) * dinv[row]) ----------------

__global__ __launch_bounds__(256) void gemm1_mfma(const float* __restrict__ x,
                                                  const float* __restrict__ W1,
                                                  const float* __restrict__ dinv,
                                                  __half* __restrict__ g1, int N) {
    int wave = threadIdx.x >> 6;
    int lane = threadIdx.x & 63;
    int R0 = blockIdx.x * 64 + wave * 16;
    if (R0 >= N) return;
    int m = lane & 15;
    int kb = (lane >> 4) * 8;
    int row = R0 + m;
    int rowc = min(row, N - 1);

    half8 bfrag[4];
#pragma unroll
    for (int kk = 0; kk < 4; ++kk) {
#pragma unroll
        for (int j = 0; j < 8; ++j)
            bfrag[kk][j] = (_Float16)W1[(kk * 32 + kb + j) * 16 + m];
    }

    const float* xr = x + (size_t)rowc * 128;
    float4 u[8];
#pragma unroll
    for (int kk = 0; kk < 4; ++kk) {
        u[2 * kk]     = *reinterpret_cast<const float4*>(xr + kk * 32 + kb);
        u[2 * kk + 1] = *reinterpret_cast<const float4*>(xr + kk * 32 + kb + 4);
    }

    f32x4 acc = {0.f, 0.f, 0.f, 0.f};
#pragma unroll
    for (int kk = 0; kk < 4; ++kk) {
        half8 a;
        a[0] = (_Float16)u[2 * kk].x;     a[1] = (_Float16)u[2 * kk].y;
        a[2] = (_Float16)u[2 * kk].z;     a[3] = (_Float16)u[2 * kk].w;
        a[4] = (_Float16)u[2 * kk + 1].x; a[5] = (_Float16)u[2 * kk + 1].y;
        a[6] = (_Float16)u[2 * kk + 1].z; a[7] = (_Float16)u[2 * kk + 1].w;
        acc = __builtin_amdgcn_mfma_f32_16x16x32_f16(a, bfrag[kk], acc, 0, 0, 0);
    }

#pragma unroll
    for (int i = 0; i < 4; ++i) {
        int r = R0 + (lane >> 4) * 4 + i;
        if (r < N) g1[(size_t)r * 16 + m] = __float2half(acc[i] * dinv[r]);
    }
}

// ---------------- gather1: (node, h, es); uint4 loads, unroll-8, eidx-pipelined ----------------

__global__ __launch_bounds__(256) void gather1_kernel(const int* __restrict__ rowptr,
                                                      const int* __restrict__ eidx,
                                                      const __half* __restrict__ g1,
                                                      const float* __restrict__ dinv,
                                                      const float* __restrict__ b1,
                                                      __half* __restrict__ g2, int N) {
    int gid = blockIdx.x * blockDim.x + threadIdx.x;
    int d = gid >> 2;
    if (d >= N) return;
    int sub = threadIdx.x & 3;
    int h = sub & 1, es = sub >> 1;
    int f0 = h * 8;
    int lo = rowptr[d], hi = rowptr[d + 1];
    // hoisted epilogue loads
    float di = dinv[d];
    uint4v svh = *reinterpret_cast<const uint4v*>(g1 + d * 16 + f0);

    float a[8] = {0, 0, 0, 0, 0, 0, 0, 0};
    int j = lo + es;
    int s[8];
    bool have = (j + 14 < hi);
    if (have) {
#pragma unroll
        for (int k = 0; k < 8; ++k) s[k] = eidx[j + 2 * k];
    }
    while (have) {
        uint4v v[8];
#pragma unroll
        for (int k = 0; k < 8; ++k)
            v[k] = *reinterpret_cast<const uint4v*>(g1 + s[k] * 16 + f0);
        int jn = j + 16;
        bool haveN = (jn + 14 < hi);
        int sn[8];
        if (haveN) {
#pragma unroll
            for (int k = 0; k < 8; ++k) sn[k] = eidx[jn + 2 * k];
        }
#pragma unroll
        for (int k = 0; k < 8; ++k) acc8(a, v[k]);
        j = jn; have = haveN;
#pragma unroll
        for (int k = 0; k < 8; ++k) s[k] = sn[k];
    }
    for (; j < hi; j += 2) {
        int sx = eidx[j];
        uint4v v = *reinterpret_cast<const uint4v*>(g1 + sx * 16 + f0);
        acc8(a, v);
    }
#pragma unroll
    for (int k = 0; k < 8; ++k) a[k] += __shfl_xor(a[k], 2);
    if (es == 0) {
        float sf[8];
        unp8(svh, sf);
        f32x4 bb0 = *reinterpret_cast<const f32x4*>(b1 + f0);
        f32x4 bb1 = *reinterpret_cast<const f32x4*>(b1 + f0 + 4);
        float o[8];
#pragma unroll
        for (int k = 0; k < 4; ++k) {
            o[k]     = fmaxf(di * (a[k] + sf[k]) + bb0[k], 0.0f) * di;
            o[k + 4] = fmaxf(di * (a[k + 4] + sf[k + 4]) + bb1[k], 0.0f) * di;
        }
        *reinterpret_cast<uint4v*>(g2 + d * 16 + f0) = pk8(o);
    }
}

// ---------------- fused gather2 + GEMM2: (node, es@bit4, h@bit5), pipelined ----------------

__global__ __launch_bounds__(256) void gather2_gemm2(const int* __restrict__ rowptr,
                                                     const int* __restrict__ eidx,
                                                     const __half* __restrict__ g2,
                                                     const float* __restrict__ dinv,
                                                     const float* __restrict__ W2,
                                                     const float* __restrict__ b2,
                                                     float* __restrict__ out, int N) {
    int gid = blockIdx.x * blockDim.x + threadIdx.x;
    int wid = gid >> 6;
    int lane = threadIdx.x & 63;
    int base = wid * 16;
    if (base >= N) return;
    int nl = lane & 15;
    int q = lane >> 4;
    int es = q & 1;
    int h = lane >> 5;
    int f0 = h * 8;
    int d = base + nl;
    int dc = min(d, N - 1);
    int lo = rowptr[dc], hi = rowptr[dc + 1];
    // hoisted epilogue loads
    float di = dinv[dc];
    uint4v svh = *reinterpret_cast<const uint4v*>(g2 + dc * 16 + f0);

    float a[8] = {0, 0, 0, 0, 0, 0, 0, 0};
    int j = lo + es;
    int s[8];
    bool have = (j + 14 < hi);
    if (have) {
#pragma unroll
        for (int k = 0; k < 8; ++k) s[k] = eidx[j + 2 * k];
    }
    while (have) {
        uint4v v[8];
#pragma unroll
        for (int k = 0; k < 8; ++k)
            v[k] = *reinterpret_cast<const uint4v*>(g2 + s[k] * 16 + f0);
        int jn = j + 16;
        bool haveN = (jn + 14 < hi);
        int sn[8];
        if (haveN) {
#pragma unroll
            for (int k = 0; k < 8; ++k) sn[k] = eidx[jn + 2 * k];
        }
#pragma unroll
        for (int k = 0; k < 8; ++k) acc8(a, v[k]);
        j = jn; have = haveN;
#pragma unroll
        for (int k = 0; k < 8; ++k) s[k] = sn[k];
    }
    for (; j < hi; j += 2) {
        int sx = eidx[j];
        uint4v v = *reinterpret_cast<const uint4v*>(g2 + sx * 16 + f0);
        acc8(a, v);
    }
#pragma unroll
    for (int k = 0; k < 8; ++k) a[k] += __shfl_xor(a[k], 16);

    float sf[8];
    unp8(svh, sf);
    float af[8];
#pragma unroll
    for (int k = 0; k < 8; ++k) af[k] = di * (a[k] + sf[k]);

    int hi4 = es * 4;
    half4 afrag;
#pragma unroll
    for (int jj = 0; jj < 4; ++jj) afrag[jj] = (_Float16)af[hi4 + jj];

    f32x4 dacc[8];
#pragma unroll
    for (int ct = 0; ct < 8; ++ct) {
        half4 bfrag;
#pragma unroll
        for (int jj = 0; jj < 4; ++jj)
            bfrag[jj] = (_Float16)W2[(q * 4 + jj) * 128 + ct * 16 + nl];
        f32x4 z = {0.f, 0.f, 0.f, 0.f};
        dacc[ct] = __builtin_amdgcn_mfma_f32_16x16x16f16(afrag, bfrag, z, 0, 0, 0);
    }

    float bias[8];
#pragma unroll
    for (int ct = 0; ct < 8; ++ct) bias[ct] = b2[ct * 16 + nl];

    int rbase = base + q * 4;
#pragma unroll
    for (int i = 0; i < 4; ++i) {
        int r = rbase + i;
        if (r < N) {
            float* orow = out + (size_t)r * 128 + nl;
#pragma unroll
            for (int ct = 0; ct < 8; ++ct) orow[ct * 16] = dacc[ct][i] + bias[ct];
        }
    }
}

// ---------------- launch ----------------

extern "C" void kernel_launch(void* const* d_in, const int* in_sizes, int n_in,
                              void* d_out, int out_size, void* d_ws, size_t ws_size,
                              hipStream_t stream) {
    const float* x  = (const float*)d_in[0];
    const int*   ei = (const int*)d_in[1];
    const float* W1 = (const float*)d_in[2];
    const float* b1 = (const float*)d_in[3];
    const float* W2 = (const float*)d_in[4];
    const float* b2 = (const float*)d_in[5];
    float* out = (float*)d_out;

    const int N = in_sizes[0] / 128;
    const int E = in_sizes[1] / 2;
    const int* src = ei;
    const int* dst = ei + E;
    const int NB = (N + RANGE - 1) / RANGE;

    // ws (4B units): [pairbuf NB*CAP][gcursor NB][bbase NB+1][rowptr N+1][eidx E][dinv N][g1 8N][g2 8N]
    unsigned* pairbuf = (unsigned*)d_ws;
    int* gcursor = (int*)(pairbuf + (size_t)NB * CAP);
    int* bbase   = gcursor + NB;
    int* rowptr  = bbase + (NB + 1);
    int* eidx    = rowptr + (N + 1);
    float* dinv  = (float*)(eidx + E);
    __half* g1 = (__half*)(dinv + N);
    __half* g2 = g1 + 16 * N;

    const int B = 256;
    init_gcursor<<<1, B, 0, stream>>>(gcursor, NB);
    binpass<<<(E + T_TILE - 1) / T_TILE, B, 0, stream>>>(src, dst, E, gcursor, pairbuf);
    bucketscan<<<1, B, 0, stream>>>(gcursor, NB, bbase, rowptr, N);
    bucket_build<<<NB, 512, 0, stream>>>(pairbuf, gcursor, bbase, N, rowptr, dinv, eidx);
    gemm1_mfma<<<(N + 63) / 64, B, 0, stream>>>(x, W1, dinv, g1, N);
    gather1_kernel<<<(N * 4 + B - 1) / B, B, 0, stream>>>(rowptr, eidx, g1, dinv, b1, g2, N);
    gather2_gemm2<<<(N * 4 + B - 1) / B, B, 0, stream>>>(rowptr, eidx, g2, dinv, W2, b2, out, N);
}

// Round 15
// 140.109 us; speedup vs baseline: 1.4141x; 1.0180x over previous
//
#include <hip/hip_runtime.h>
#include <hip/hip_fp16.h>

typedef _Float16 half8 __attribute__((ext_vector_type(8)));
typedef _Float16 half4 __attribute__((ext_vector_type(4)));
typedef float f32x4 __attribute__((ext_vector_type(4)));
typedef unsigned uint4v __attribute__((ext_vector_type(4)));

// ---------- binned CSR build ----------
#define RANGE    512
#define RSH      9
#define CAP      17408          // mean E/NB=16327 + 8 sigma
#define T_TILE   4096           // edges per binpass block (256 thr x 16)

__global__ void init_gcursor(int* __restrict__ gcursor, int NB) {
    int t = blockIdx.x * blockDim.x + threadIdx.x;
    if (t < NB) gcursor[t] = t * CAP;
}

// ---------------- fat kernel: binpass (blocks < binBlocks) || gemm1 raw (rest) ----------------
// gemm1 part: g1 = fp16(x @ W1), unscaled (dinv applied later by scale_g1).

__global__ __launch_bounds__(256) void binpass_gemm1(const int* __restrict__ src,
                                                     const int* __restrict__ dst, int E,
                                                     int* __restrict__ gcursor,
                                                     unsigned* __restrict__ pairbuf,
                                                     int binBlocks,
                                                     const float* __restrict__ x,
                                                     const float* __restrict__ W1,
                                                     __half* __restrict__ g1, int N) {
    if (blockIdx.x >= binBlocks) {
        // ---- gemm1 raw ----
        int wave = threadIdx.x >> 6;
        int lane = threadIdx.x & 63;
        int R0 = (blockIdx.x - binBlocks) * 64 + wave * 16;
        if (R0 >= N) return;
        int m = lane & 15;
        int kb = (lane >> 4) * 8;
        int row = R0 + m;
        int rowc = min(row, N - 1);

        half8 bfrag[4];
#pragma unroll
        for (int kk = 0; kk < 4; ++kk) {
#pragma unroll
            for (int j = 0; j < 8; ++j)
                bfrag[kk][j] = (_Float16)W1[(kk * 32 + kb + j) * 16 + m];
        }
        const float* xr = x + (size_t)rowc * 128;
        float4 u[8];
#pragma unroll
        for (int kk = 0; kk < 4; ++kk) {
            u[2 * kk]     = *reinterpret_cast<const float4*>(xr + kk * 32 + kb);
            u[2 * kk + 1] = *reinterpret_cast<const float4*>(xr + kk * 32 + kb + 4);
        }
        f32x4 acc = {0.f, 0.f, 0.f, 0.f};
#pragma unroll
        for (int kk = 0; kk < 4; ++kk) {
            half8 a;
            a[0] = (_Float16)u[2 * kk].x;     a[1] = (_Float16)u[2 * kk].y;
            a[2] = (_Float16)u[2 * kk].z;     a[3] = (_Float16)u[2 * kk].w;
            a[4] = (_Float16)u[2 * kk + 1].x; a[5] = (_Float16)u[2 * kk + 1].y;
            a[6] = (_Float16)u[2 * kk + 1].z; a[7] = (_Float16)u[2 * kk + 1].w;
            acc = __builtin_amdgcn_mfma_f32_16x16x32_f16(a, bfrag[kk], acc, 0, 0, 0);
        }
#pragma unroll
        for (int i = 0; i < 4; ++i) {
            int r = R0 + (lane >> 4) * 4 + i;
            if (r < N) g1[(size_t)r * 16 + m] = __float2half(acc[i]);
        }
        return;
    }
    // ---- binpass ----
    __shared__ unsigned sbuf[T_TILE];
    __shared__ unsigned char sbk[T_TILE];
    __shared__ int lcount[256], loff[256], lplace[256], gbase[256];
    int t = threadIdx.x;
    int base = blockIdx.x * T_TILE;
    int ecount = min(T_TILE, E - base);

    lcount[t] = 0;
    __syncthreads();

    unsigned pk[16];
    int bn[16];
#pragma unroll
    for (int k4 = 0; k4 < 4; ++k4) {
        int i = base + (t + k4 * 256) * 4;
        if (i + 3 < E) {
            int4 sv = *reinterpret_cast<const int4*>(src + i);
            int4 dv = *reinterpret_cast<const int4*>(dst + i);
            int ss[4] = {sv.x, sv.y, sv.z, sv.w};
            int dd[4] = {dv.x, dv.y, dv.z, dv.w};
#pragma unroll
            for (int m = 0; m < 4; ++m) {
                int k = k4 * 4 + m;
                bn[k] = dd[m] >> RSH;
                pk[k] = ((unsigned)ss[m] << RSH) | (unsigned)(dd[m] & (RANGE - 1));
                atomicAdd(&lcount[bn[k]], 1);
            }
        } else {
#pragma unroll
            for (int m = 0; m < 4; ++m) {
                int k = k4 * 4 + m;
                int ii = i + m;
                if (ii < E) {
                    int s = src[ii], d = dst[ii];
                    bn[k] = d >> RSH;
                    pk[k] = ((unsigned)s << RSH) | (unsigned)(d & (RANGE - 1));
                    atomicAdd(&lcount[bn[k]], 1);
                } else bn[k] = -1;
            }
        }
    }
    __syncthreads();
    loff[t] = lcount[t];
    __syncthreads();
    for (int off = 1; off < 256; off <<= 1) {
        int u = (t >= off) ? loff[t - off] : 0;
        __syncthreads();
        loff[t] += u;
        __syncthreads();
    }
    int ex = loff[t] - lcount[t];
    __syncthreads();
    loff[t] = ex;
    lplace[t] = ex;
    if (lcount[t] > 0) gbase[t] = atomicAdd(&gcursor[t], lcount[t]);
    __syncthreads();
#pragma unroll
    for (int k = 0; k < 16; ++k) {
        if (bn[k] >= 0) {
            int pos = atomicAdd(&lplace[bn[k]], 1);
            sbuf[pos] = pk[k];
            sbk[pos] = (unsigned char)bn[k];
        }
    }
    __syncthreads();
    for (int i = t; i < ecount; i += 256) {
        int b = sbk[i];
        pairbuf[gbase[b] + (i - loff[b])] = sbuf[i];
    }
}

__global__ __launch_bounds__(256) void bucketscan(const int* __restrict__ gcursor, int NB,
                                                  int* __restrict__ bbase,
                                                  int* __restrict__ rowptr, int N) {
    __shared__ int sd[256];
    int t = threadIdx.x;
    int c = (t < NB) ? (gcursor[t] - t * CAP) : 0;
    sd[t] = c;
    __syncthreads();
    for (int off = 1; off < 256; off <<= 1) {
        int u = (t >= off) ? sd[t - off] : 0;
        __syncthreads();
        sd[t] += u;
        __syncthreads();
    }
    if (t < NB) bbase[t] = sd[t] - c;
    if (t == 255) { bbase[NB] = sd[255]; rowptr[N] = sd[255]; }
}

__global__ __launch_bounds__(512) void bucket_build(const unsigned* __restrict__ pairbuf,
                                                    const int* __restrict__ gcursor,
                                                    const int* __restrict__ bbase, int N,
                                                    int* __restrict__ rowptr,
                                                    float* __restrict__ dinv,
                                                    int* __restrict__ eidx) {
    __shared__ int lcnt[RANGE];
    __shared__ int lsc[RANGE];
    int b = blockIdx.x, t = threadIdx.x;
    int cnt = gcursor[b] - b * CAP;
    const unsigned* pb = pairbuf + (size_t)b * CAP;

    lcnt[t] = 0;
    __syncthreads();
    for (int i = t; i < cnt; i += 512) atomicAdd(&lcnt[pb[i] & (RANGE - 1)], 1);
    __syncthreads();
    lsc[t] = lcnt[t];
    __syncthreads();
    for (int off = 1; off < 512; off <<= 1) {
        int u = (t >= off) ? lsc[t - off] : 0;
        __syncthreads();
        lsc[t] += u;
        __syncthreads();
    }
    int ex = lsc[t] - lcnt[t];
    int gb = bbase[b];
    int node = b * RANGE + t;
    if (node < N) {
        rowptr[node] = gb + ex;
        dinv[node] = rsqrtf((float)lcnt[t] + 1.0f);
    }
    __syncthreads();
    lsc[t] = gb + ex;
    __syncthreads();
    for (int i = t; i < cnt; i += 512) {
        unsigned p = pb[i];
        int pos = atomicAdd(&lsc[p & (RANGE - 1)], 1);
        eidx[pos] = (int)(p >> RSH);
    }
}

// ---------- helpers ----------

__device__ __forceinline__ void unp8(uint4v v, float* f) {
#pragma unroll
    for (int k = 0; k < 4; ++k) {
        unsigned w = v[k];
        __half2 h2 = *reinterpret_cast<__half2*>(&w);
        float2 t = __half22float2(h2);
        f[2 * k] = t.x; f[2 * k + 1] = t.y;
    }
}

__device__ __forceinline__ void acc8(float* a, uint4v v) {
#pragma unroll
    for (int k = 0; k < 4; ++k) {
        unsigned w = v[k];
        __half2 h2 = *reinterpret_cast<__half2*>(&w);
        float2 t = __half22float2(h2);
        a[2 * k]     += t.x;
        a[2 * k + 1] += t.y;
    }
}

__device__ __forceinline__ uint4v pk8(const float* o) {
    uint4v r;
#pragma unroll
    for (int k = 0; k < 4; ++k) {
        __half2 h2 = __floats2half2_rn(o[2 * k], o[2 * k + 1]);
        r[k] = *reinterpret_cast<unsigned*>(&h2);
    }
    return r;
}

// ---------------- scale_g1: g1 *= dinv[node] (8 halves per thread) ----------------

__global__ __launch_bounds__(256) void scale_g1(__half* __restrict__ g1,
                                                const float* __restrict__ dinv, int N) {
    int gid = blockIdx.x * blockDim.x + threadIdx.x;
    if (gid >= N * 2) return;
    int node = gid >> 1, f0 = (gid & 1) * 8;
    float di = dinv[node];
    uint4v v = *reinterpret_cast<const uint4v*>(g1 + node * 16 + f0);
    float f[8];
    unp8(v, f);
#pragma unroll
    for (int k = 0; k < 8; ++k) f[k] *= di;
    *reinterpret_cast<uint4v*>(g1 + node * 16 + f0) = pk8(f);
}

// ---------------- gather1: 8 lanes/node (h x es4); uint4 loads, unroll-8 ----------------

__global__ __launch_bounds__(256) void gather1_kernel(const int* __restrict__ rowptr,
                                                      const int* __restrict__ eidx,
                                                      const __half* __restrict__ g1,
                                                      const float* __restrict__ dinv,
                                                      const float* __restrict__ b1,
                                                      __half* __restrict__ g2, int N) {
    int gid = blockIdx.x * blockDim.x + threadIdx.x;
    int d = gid >> 3;
    if (d >= N) return;
    int sub = threadIdx.x & 7;
    int h = sub & 1, es = sub >> 1;      // es in 0..3
    int f0 = h * 8;
    int lo = rowptr[d], hi = rowptr[d + 1];
    float di = dinv[d];
    uint4v svh = *reinterpret_cast<const uint4v*>(g1 + d * 16 + f0);

    float a[8] = {0, 0, 0, 0, 0, 0, 0, 0};
    int j = lo + es;
    for (; j + 28 < hi; j += 32) {
        int s[8];
#pragma unroll
        for (int k = 0; k < 8; ++k) s[k] = eidx[j + 4 * k];
        uint4v v[8];
#pragma unroll
        for (int k = 0; k < 8; ++k)
            v[k] = *reinterpret_cast<const uint4v*>(g1 + s[k] * 16 + f0);
#pragma unroll
        for (int k = 0; k < 8; ++k) acc8(a, v[k]);
    }
    for (; j < hi; j += 4) {
        int s = eidx[j];
        uint4v v = *reinterpret_cast<const uint4v*>(g1 + s * 16 + f0);
        acc8(a, v);
    }
#pragma unroll
    for (int k = 0; k < 8; ++k) {
        a[k] += __shfl_xor(a[k], 2);
        a[k] += __shfl_xor(a[k], 4);
    }
    if (es == 0) {
        float sf[8];
        unp8(svh, sf);
        f32x4 bb0 = *reinterpret_cast<const f32x4*>(b1 + f0);
        f32x4 bb1 = *reinterpret_cast<const f32x4*>(b1 + f0 + 4);
        float o[8];
#pragma unroll
        for (int k = 0; k < 4; ++k) {
            o[k]     = fmaxf(di * (a[k] + sf[k]) + bb0[k], 0.0f) * di;
            o[k + 4] = fmaxf(di * (a[k + 4] + sf[k + 4]) + bb1[k], 0.0f) * di;
        }
        *reinterpret_cast<uint4v*>(g2 + d * 16 + f0) = pk8(o);
    }
}

// ---------------- fused gather2 + GEMM2 (R13 form): (node, es@bit4, h@bit5) ----------------

__global__ __launch_bounds__(256) void gather2_gemm2(const int* __restrict__ rowptr,
                                                     const int* __restrict__ eidx,
                                                     const __half* __restrict__ g2,
                                                     const float* __restrict__ dinv,
                                                     const float* __restrict__ W2,
                                                     const float* __restrict__ b2,
                                                     float* __restrict__ out, int N) {
    int gid = blockIdx.x * blockDim.x + threadIdx.x;
    int wid = gid >> 6;
    int lane = threadIdx.x & 63;
    int base = wid * 16;
    if (base >= N) return;
    int nl = lane & 15;
    int q = lane >> 4;
    int es = q & 1;
    int h = lane >> 5;
    int f0 = h * 8;
    int d = base + nl;
    int dc = min(d, N - 1);
    int lo = rowptr[dc], hi = rowptr[dc + 1];

    float a[8] = {0, 0, 0, 0, 0, 0, 0, 0};
    int j = lo + es;
    for (; j + 14 < hi; j += 16) {
        int s[8];
#pragma unroll
        for (int k = 0; k < 8; ++k) s[k] = eidx[j + 2 * k];
        uint4v v[8];
#pragma unroll
        for (int k = 0; k < 8; ++k)
            v[k] = *reinterpret_cast<const uint4v*>(g2 + s[k] * 16 + f0);
#pragma unroll
        for (int k = 0; k < 8; ++k) acc8(a, v[k]);
    }
    for (; j < hi; j += 2) {
        int s = eidx[j];
        uint4v v = *reinterpret_cast<const uint4v*>(g2 + s * 16 + f0);
        acc8(a, v);
    }
#pragma unroll
    for (int k = 0; k < 8; ++k) a[k] += __shfl_xor(a[k], 16);

    float di = dinv[dc];
    uint4v sv = *reinterpret_cast<const uint4v*>(g2 + dc * 16 + f0);
    float sf[8];
    unp8(sv, sf);
    float af[8];
#pragma unroll
    for (int k = 0; k < 8; ++k) af[k] = di * (a[k] + sf[k]);

    int hi4 = es * 4;
    half4 afrag;
#pragma unroll
    for (int jj = 0; jj < 4; ++jj) afrag[jj] = (_Float16)af[hi4 + jj];

    f32x4 dacc[8];
#pragma unroll
    for (int ct = 0; ct < 8; ++ct) {
        half4 bfrag;
#pragma unroll
        for (int jj = 0; jj < 4; ++jj)
            bfrag[jj] = (_Float16)W2[(q * 4 + jj) * 128 + ct * 16 + nl];
        f32x4 z = {0.f, 0.f, 0.f, 0.f};
        dacc[ct] = __builtin_amdgcn_mfma_f32_16x16x16f16(afrag, bfrag, z, 0, 0, 0);
    }

    float bias[8];
#pragma unroll
    for (int ct = 0; ct < 8; ++ct) bias[ct] = b2[ct * 16 + nl];

    int rbase = base + q * 4;
#pragma unroll
    for (int i = 0; i < 4; ++i) {
        int r = rbase + i;
        if (r < N) {
            float* orow = out + (size_t)r * 128 + nl;
#pragma unroll
            for (int ct = 0; ct < 8; ++ct) orow[ct * 16] = dacc[ct][i] + bias[ct];
        }
    }
}

// ---------------- launch ----------------

extern "C" void kernel_launch(void* const* d_in, const int* in_sizes, int n_in,
                              void* d_out, int out_size, void* d_ws, size_t ws_size,
                              hipStream_t stream) {
    const float* x  = (const float*)d_in[0];
    const int*   ei = (const int*)d_in[1];
    const float* W1 = (const float*)d_in[2];
    const float* b1 = (const float*)d_in[3];
    const float* W2 = (const float*)d_in[4];
    const float* b2 = (const float*)d_in[5];
    float* out = (float*)d_out;

    const int N = in_sizes[0] / 128;
    const int E = in_sizes[1] / 2;
    const int* src = ei;
    const int* dst = ei + E;
    const int NB = (N + RANGE - 1) / RANGE;

    // ws (4B units): [pairbuf NB*CAP][gcursor NB][bbase NB+1][rowptr N+1][eidx E][dinv N][g1 8N][g2 8N]
    unsigned* pairbuf = (unsigned*)d_ws;
    int* gcursor = (int*)(pairbuf + (size_t)NB * CAP);
    int* bbase   = gcursor + NB;
    int* rowptr  = bbase + (NB + 1);
    int* eidx    = rowptr + (N + 1);
    float* dinv  = (float*)(eidx + E);
    __half* g1 = (__half*)(dinv + N);
    __half* g2 = g1 + 16 * N;

    const int B = 256;
    const int binBlocks  = (E + T_TILE - 1) / T_TILE;
    const int gemmBlocks = (N + 63) / 64;
    init_gcursor<<<1, B, 0, stream>>>(gcursor, NB);
    binpass_gemm1<<<binBlocks + gemmBlocks, B, 0, stream>>>(src, dst, E, gcursor, pairbuf,
                                                            binBlocks, x, W1, g1, N);
    bucketscan<<<1, B, 0, stream>>>(gcursor, NB, bbase, rowptr, N);
    bucket_build<<<NB, 512, 0, stream>>>(pairbuf, gcursor, bbase, N, rowptr, dinv, eidx);
    scale_g1<<<(N * 2 + B - 1) / B, B, 0, stream>>>(g1, dinv, N);
    gather1_kernel<<<(N * 8 + B - 1) / B, B, 0, stream>>>(rowptr, eidx, g1, dinv, b1, g2, N);
    gather2_gemm2<<<(N * 4 + B - 1) / B, B, 0, stream>>>(rowptr, eidx, g2, dinv, W2, b2, out, N);
}